// Round 1
// baseline (74.879 us; speedup 1.0000x reference)
//
#include <hip/hip_runtime.h>

#ifndef __has_builtin
#define __has_builtin(x) 0
#endif

__device__ __forceinline__ float fexp2(float x) {
#if __has_builtin(__builtin_amdgcn_exp2f)
    return __builtin_amdgcn_exp2f(x);   // v_exp_f32: 2^x
#else
    return exp2f(x);
#endif
}

__device__ __forceinline__ float fcos_rev(float r) {
#if __has_builtin(__builtin_amdgcn_cosf)
    return __builtin_amdgcn_cosf(r);    // v_cos_f32: cos(2*pi*r), r in revolutions
#else
    return __cosf(r * 6.283185307179586f);
#endif
}

constexpr int NATOMS = 512;
constexpr int NP     = 16;

// shifts: 0.9 + 0.26875*p, stored explicitly to match np.float32 table
__device__ __constant__ float c_shf[NP] = {
    0.9f, 1.16875f, 1.4375f, 1.70625f, 1.975f, 2.24375f, 2.5125f, 2.78125f,
    3.05f, 3.31875f, 3.5875f, 3.85625f, 4.125f, 4.39375f, 4.6625f, 4.93125f
};

__global__ __launch_bounds__(256) void aev_radial_kernel(
        const float* __restrict__ d,   // (B, N, N)
        const float* __restrict__ z,   // (B, N)
        float* __restrict__ out)       // (B, N, NP)
{
    const int lane = threadIdx.x & 63;
    const int wave = threadIdx.x >> 6;
    const int row  = blockIdx.x * 4 + wave;      // row = b*N + i, in [0, 8192)
    const int b    = row >> 9;                   // N = 512

    const float4* __restrict__ dd = reinterpret_cast<const float4*>(d + (size_t)row * NATOMS);
    const float4* __restrict__ zz = reinterpret_cast<const float4*>(z + (size_t)b   * NATOMS);

    const float C   = -23.083120654223414f;      // -16 * log2(e)
    const float REV = 0.09615384615384616f;      // 1 / (2 * 5.2): d*REV in [0,1) revolutions

    float acc[NP];
#pragma unroll
    for (int p = 0; p < NP; ++p) acc[p] = 0.0f;

#pragma unroll
    for (int h = 0; h < 2; ++h) {
        float4 dv4 = dd[lane + 64 * h];
        float4 zv4 = zz[lane + 64 * h];
#pragma unroll
        for (int q = 0; q < 4; ++q) {
            float dv = (&dv4.x)[q];
            float zv = (&zv4.x)[q];
            bool valid = (dv < 5.2f) && (dv != 0.0f);
            float fc = fmaf(0.5f, fcos_rev(dv * REV), 0.5f);
            float w  = valid ? zv * fc : 0.0f;
            // w==0 lanes: exp2 arg <= 0 -> finite (underflows to 0), fma adds 0. Safe.
#pragma unroll
            for (int p = 0; p < NP; ++p) {
                float t = dv - c_shf[p];
                float e = fexp2((C * t) * t);
                acc[p] = fmaf(w, e, acc[p]);
            }
        }
    }

    // Lane-halving butterfly: halve acc count while reducing over lanes.
    // After 4 steps each lane holds one value (acc index = rev4(lane&15))
    // summed over its 16-lane group; 2 more shfl steps cover all 64 lanes.
    bool u;
    float r0[8];
    u = (lane & 1) != 0;
#pragma unroll
    for (int k = 0; k < 8; ++k) {
        float snd  = u ? acc[k] : acc[k + 8];
        float rcv  = __shfl_xor(snd, 1, 64);
        float kept = u ? acc[k + 8] : acc[k];
        r0[k] = kept + rcv;
    }
    float r1[4];
    u = (lane & 2) != 0;
#pragma unroll
    for (int k = 0; k < 4; ++k) {
        float snd  = u ? r0[k] : r0[k + 4];
        float rcv  = __shfl_xor(snd, 2, 64);
        float kept = u ? r0[k + 4] : r0[k];
        r1[k] = kept + rcv;
    }
    float r2[2];
    u = (lane & 4) != 0;
#pragma unroll
    for (int k = 0; k < 2; ++k) {
        float snd  = u ? r1[k] : r1[k + 2];
        float rcv  = __shfl_xor(snd, 4, 64);
        float kept = u ? r1[k + 2] : r1[k];
        r2[k] = kept + rcv;
    }
    float r3;
    u = (lane & 8) != 0;
    {
        float snd  = u ? r2[0] : r2[1];
        float rcv  = __shfl_xor(snd, 8, 64);
        float kept = u ? r2[1] : r2[0];
        r3 = kept + rcv;
    }
    r3 += __shfl_xor(r3, 16, 64);
    r3 += __shfl_xor(r3, 32, 64);

    // acc index held by this lane: bit-reversal of (lane & 15)
    int idx = ((lane & 1) << 3) | ((lane & 2) << 1) | ((lane & 4) >> 1) | ((lane & 8) >> 3);
    if (lane < 16) {
        out[(size_t)row * NP + idx] = r3;
    }
}

extern "C" void kernel_launch(void* const* d_in, const int* in_sizes, int n_in,
                              void* d_out, int out_size, void* d_ws, size_t ws_size,
                              hipStream_t stream) {
    const float* d  = (const float*)d_in[0];   // (16, 512, 512) fp32
    const float* z  = (const float*)d_in[1];   // (16, 512) fp32
    float* out      = (float*)d_out;           // (16, 512, 16) fp32

    // 8192 rows, one wave each, 4 waves per block -> 2048 blocks
    aev_radial_kernel<<<dim3(2048), dim3(256), 0, stream>>>(d, z, out);
}

// Round 2
// 69.063 us; speedup vs baseline: 1.0842x; 1.0842x over previous
//
#include <hip/hip_runtime.h>

#ifndef __has_builtin
#define __has_builtin(x) 0
#endif

__device__ __forceinline__ float fexp2(float x) {
#if __has_builtin(__builtin_amdgcn_exp2f)
    return __builtin_amdgcn_exp2f(x);   // v_exp_f32: 2^x
#else
    return exp2f(x);
#endif
}

__device__ __forceinline__ float fcos_rev(float r) {
#if __has_builtin(__builtin_amdgcn_cosf)
    return __builtin_amdgcn_cosf(r);    // v_cos_f32: cos(2*pi*r), r in revolutions
#else
    return __cosf(r * 6.283185307179586f);
#endif
}

constexpr int NATOMS = 512;
constexpr int NP     = 16;

// eta=16, delta=0.26875, shifts s_p = 0.9 + p*delta, anchors s_4=1.975, s_12=4.125
// Gaussian chain in base-2 domain:
//   g_p       = 2^(C * t_p^2),              C = -eta*log2(e)        = -23.083120654223414
//   g_{p+1}   = g_p * w_p,  w_p = 2^(A*t_p + B),
//               A = 2*eta*delta*log2(e) = 12.407177351645085
//               B = -eta*delta^2*log2(e) = -1.6672144566
//   w_{p+1}   = w_p * k2,   k2  = 2^(-A*delta) = 2^(-3.3344289132)
//   g_{p-1}   = g_p * v_p,  v_p = 2^(-A*t_p + B),  v_{p-1} = v_p * k2
// Upper-anchor factors derive from lower's: t_12 = t_4 - 2.15,
//   w_hi = w_lo * 2^(-A*2.15), v_hi = v_lo * 2^(+A*2.15), A*2.15 = 26.675431306

__device__ __forceinline__ void process_elem(float dv, float zv, float* acc,
                                             float k2, float cwh, float cvh) {
    const float C   = -23.083120654223414f;
    const float A   = 12.407177351645085f;
    const float B   = -1.6672144566f;
    const float REV = 0.09615384615384616f;   // 1/(2*5.2), cos arg in revolutions

    bool  valid = (dv < 5.2f) && (dv != 0.0f);
    float fc    = fmaf(0.5f, fcos_rev(dv * REV), 0.5f);
    float we    = valid ? zv * fc : 0.0f;

    float tl = dv - 1.975f;                   // t_4
    float th = dv - 4.125f;                   // t_12
    float gl = we * fexp2((C * tl) * tl);     // g_4 * we
    float gh = we * fexp2((C * th) * th);     // g_12 * we
    float wl = fexp2(fmaf(A, tl, B));         // w_4
    float vl = fexp2(fmaf(-A, tl, B));        // v_4
    float wh = wl * cwh;                      // w_12
    float vh = vl * cvh;                      // v_12

    // lower half, anchor p=4
    acc[4] += gl;
    float g = gl * wl; acc[5] += g; wl *= k2; // g_5
    g = g * wl;        acc[6] += g; wl *= k2; // g_6
    g = g * wl;        acc[7] += g;           // g_7
    g = gl * vl;       acc[3] += g; vl *= k2; // g_3
    g = g * vl;        acc[2] += g; vl *= k2; // g_2
    g = g * vl;        acc[1] += g; vl *= k2; // g_1
    g = g * vl;        acc[0] += g;           // g_0

    // upper half, anchor p=12
    acc[12] += gh;
    g = gh * wh;       acc[13] += g; wh *= k2;
    g = g * wh;        acc[14] += g; wh *= k2;
    g = g * wh;        acc[15] += g;
    g = gh * vh;       acc[11] += g; vh *= k2;
    g = g * vh;        acc[10] += g; vh *= k2;
    g = g * vh;        acc[9]  += g; vh *= k2;
    g = g * vh;        acc[8]  += g;
}

__global__ __launch_bounds__(256, 4) void aev_radial_kernel(
        const float* __restrict__ d,   // (B, N, N)
        const float* __restrict__ z,   // (B, N)
        float* __restrict__ out)       // (B, N, NP)
{
    const int lane = threadIdx.x & 63;
    const int wave = threadIdx.x >> 6;
    const int row  = blockIdx.x * 4 + wave;      // row = b*N + i, in [0, 8192)
    const int b    = row >> 9;                   // N = 512

    const float4* __restrict__ dd = reinterpret_cast<const float4*>(d + (size_t)row * NATOMS);
    const float4* __restrict__ zz = reinterpret_cast<const float4*>(z + (size_t)b   * NATOMS);

    // loop-invariant chain constants (3 extra trans per thread — negligible)
    const float k2  = fexp2(-3.3344289132f);
    const float cwh = fexp2(-26.675431306f);
    const float cvh = fexp2( 26.675431306f);

    float acc[NP];
#pragma unroll
    for (int p = 0; p < NP; ++p) acc[p] = 0.0f;

#pragma unroll
    for (int h = 0; h < 2; ++h) {
        float4 dv4 = dd[lane + 64 * h];
        float4 zv4 = zz[lane + 64 * h];
        process_elem(dv4.x, zv4.x, acc, k2, cwh, cvh);
        process_elem(dv4.y, zv4.y, acc, k2, cwh, cvh);
        process_elem(dv4.z, zv4.z, acc, k2, cwh, cvh);
        process_elem(dv4.w, zv4.w, acc, k2, cwh, cvh);
    }

    // Lane-halving butterfly reduction (as round 0)
    bool u;
    float r0[8];
    u = (lane & 1) != 0;
#pragma unroll
    for (int k = 0; k < 8; ++k) {
        float snd  = u ? acc[k] : acc[k + 8];
        float rcv  = __shfl_xor(snd, 1, 64);
        float kept = u ? acc[k + 8] : acc[k];
        r0[k] = kept + rcv;
    }
    float r1[4];
    u = (lane & 2) != 0;
#pragma unroll
    for (int k = 0; k < 4; ++k) {
        float snd  = u ? r1[0] : r1[0]; // placeholder avoided below
        (void)snd;
        float s2   = u ? r0[k] : r0[k + 4];
        float rcv  = __shfl_xor(s2, 2, 64);
        float kept = u ? r0[k + 4] : r0[k];
        r1[k] = kept + rcv;
    }
    float r2[2];
    u = (lane & 4) != 0;
#pragma unroll
    for (int k = 0; k < 2; ++k) {
        float s2   = u ? r1[k] : r1[k + 2];
        float rcv  = __shfl_xor(s2, 4, 64);
        float kept = u ? r1[k + 2] : r1[k];
        r2[k] = kept + rcv;
    }
    float r3;
    u = (lane & 8) != 0;
    {
        float s2   = u ? r2[0] : r2[1];
        float rcv  = __shfl_xor(s2, 8, 64);
        float kept = u ? r2[1] : r2[0];
        r3 = kept + rcv;
    }
    r3 += __shfl_xor(r3, 16, 64);
    r3 += __shfl_xor(r3, 32, 64);

    // acc index held by this lane: bit-reversal of (lane & 15)
    int idx = ((lane & 1) << 3) | ((lane & 2) << 1) | ((lane & 4) >> 1) | ((lane & 8) >> 3);
    if (lane < 16) {
        out[(size_t)row * NP + idx] = r3;
    }
}

extern "C" void kernel_launch(void* const* d_in, const int* in_sizes, int n_in,
                              void* d_out, int out_size, void* d_ws, size_t ws_size,
                              hipStream_t stream) {
    const float* d  = (const float*)d_in[0];   // (16, 512, 512) fp32
    const float* z  = (const float*)d_in[1];   // (16, 512) fp32
    float* out      = (float*)d_out;           // (16, 512, 16) fp32

    // 8192 rows, one wave each, 4 waves per block -> 2048 blocks
    aev_radial_kernel<<<dim3(2048), dim3(256), 0, stream>>>(d, z, out);
}